// Round 2
// baseline (654.570 us; speedup 1.0000x reference)
//
#include <hip/hip_runtime.h>
#include <cmath>

#define NN 50000
#define NE 800000
#define NH 8
#define SLOPE 0.2f

// workspace layout (fp32 elements)
#define OFF_H    0           // h:   6,400,000
#define OFF_AL   6400000     // al:    400,000
#define OFF_AR   6800000     // ar:    400,000
#define OFF_NUM  7200000     // num: 6,400,000
#define OFF_DEN  13600000    // den:   400,000
#define OFF_DEG  14000000    // deg:    50,000
#define N_ZERO   6850000     // num+den+deg contiguous zero region

__global__ void init_kernel(float* __restrict__ ws) {
    int tid = blockIdx.x * blockDim.x + threadIdx.x;
    if (tid < N_ZERO) ws[OFF_NUM + tid] = 0.0f;
}

// h = X @ W^T + b ; al[n,hd] = h[n,hd,:].a[:16] ; ar[n,hd] = h[n,hd,:].a[16:]
// One 32-thread group per node; X row in registers (shfl broadcast); W fp32 in LDS,
// transposed with a (4k mod 128) rotation so staging writes are only 8-way conflicted.
#define NPB 64   // nodes per block (8 groups x 8 iterations)
__global__ __launch_bounds__(256) void project_kernel(
    const float* __restrict__ X,   // [NN,128]
    const float* __restrict__ W,   // [128,128] row-major: W[o][k]
    const float* __restrict__ B,   // [128]
    const float* __restrict__ A,   // [32]
    float* __restrict__ h, float* __restrict__ al, float* __restrict__ ar)
{
    __shared__ float Ws[128 * 128];  // 64KB: Ws[k*128 + ((o + 4k) & 127)] = W[o][k]
    const int tid = threadIdx.x;

    for (int i = tid; i < 128 * 128; i += 256) {
        int o = i >> 7, k = i & 127;
        Ws[(k << 7) + ((o + (k << 2)) & 127)] = W[i];
    }
    __syncthreads();

    const int t32 = tid & 31;   // thread within node-group
    const int grp = tid >> 5;   // group 0..7
    const int o4 = t32 << 2;    // 4 consecutive output features
    float aL[4], aR[4], bv[4];
#pragma unroll
    for (int i = 0; i < 4; i++) {
        int f = (o4 + i) & 15;
        aL[i] = A[f];
        aR[i] = A[16 + f];
        bv[i] = B[o4 + i];
    }

    const int nodeBase = blockIdx.x * NPB;
    for (int it = 0; it < NPB / 8; ++it) {
        int gn = nodeBase + (it << 3) + grp;   // uniform across the 32-thread group
        if (gn >= NN) continue;

        float xr[4];
#pragma unroll
        for (int j = 0; j < 4; j++) xr[j] = X[(gn << 7) + (j << 5) + t32];

        float acc0 = bv[0], acc1 = bv[1], acc2 = bv[2], acc3 = bv[3];
#pragma unroll
        for (int kk = 0; kk < 4; kk++) {
            float xrk = xr[kk];
#pragma unroll
            for (int k2 = 0; k2 < 32; k2++) {
                int k = (kk << 5) + k2;
                float xv = __shfl(xrk, k2, 32);
                const float4 wr = *(const float4*)&Ws[(k << 7) + ((o4 + (k << 2)) & 127)];
                acc0 = fmaf(xv, wr.x, acc0);
                acc1 = fmaf(xv, wr.y, acc1);
                acc2 = fmaf(xv, wr.z, acc2);
                acc3 = fmaf(xv, wr.w, acc3);
            }
        }
        *(float4*)&h[(gn << 7) + o4] = make_float4(acc0, acc1, acc2, acc3);

        float p = fmaf(acc0, aL[0], fmaf(acc1, aL[1], fmaf(acc2, aL[2], acc3 * aL[3])));
        float q = fmaf(acc0, aR[0], fmaf(acc1, aR[1], fmaf(acc2, aR[2], acc3 * aR[3])));
        p += __shfl_down(p, 2, 4);
        p += __shfl_down(p, 1, 4);
        q += __shfl_down(q, 2, 4);
        q += __shfl_down(q, 1, 4);
        if ((t32 & 3) == 0) {
            al[gn * 8 + (t32 >> 2)] = p;
            ar[gn * 8 + (t32 >> 2)] = q;
        }
    }
}

// per (edge, channel): num[tgt,c] += exp(e)*h[src,c]; den[tgt,hd] += exp(e); deg[tgt]++
// No max-subtraction: e ~ N(0,1) so exp cannot overflow (clamped defensively);
// softmax ratios are mathematically identical to the reference's shifted version.
__global__ void edge_acc_kernel(const int* __restrict__ ei,
                                const float* __restrict__ al,
                                const float* __restrict__ ar,
                                const float* __restrict__ h,
                                float* __restrict__ num,
                                float* __restrict__ den,
                                float* __restrict__ deg)
{
    int tid = blockIdx.x * blockDim.x + threadIdx.x;
    if (tid >= NE * 128) return;   // 102,400,000
    int e = tid >> 7, c = tid & 127;
    int hh = c >> 4;
    int src = ei[e], tgt = ei[NE + e];
    float v = al[tgt * 8 + hh] + ar[src * 8 + hh];
    v = v > 0.0f ? v : SLOPE * v;
    float ex = __expf(fminf(v, 60.0f));
    atomicAdd(&num[(tgt << 7) + c], ex * h[(src << 7) + c]);
    if ((c & 15) == 0) atomicAdd(&den[tgt * 8 + hh], ex);
    if (c == 0) atomicAdd(&deg[tgt], 1.0f);
}

// out = elu(num/den + deg*h_i)
__global__ void finalize_kernel(const float* __restrict__ num,
                                const float* __restrict__ den,
                                const float* __restrict__ deg,
                                const float* __restrict__ h,
                                float* __restrict__ out)
{
    int tid = blockIdx.x * blockDim.x + threadIdx.x;
    if (tid >= NN * 128) return;
    int n = tid >> 7, c = tid & 127;
    float d = den[n * 8 + (c >> 4)];
    float acc = (d > 0.0f) ? num[tid] / d : 0.0f;
    acc = fmaf(deg[n], h[tid], acc);
    float r = acc > 0.0f ? acc : expm1f(acc);
    out[tid] = r;
}

extern "C" void kernel_launch(void* const* d_in, const int* in_sizes, int n_in,
                              void* d_out, int out_size, void* d_ws, size_t ws_size,
                              hipStream_t stream) {
    const float* X = (const float*)d_in[0];   // fp32 [NN,128]
    const int* ei  = (const int*)d_in[1];     // int32 [2,NE]
    const float* W = (const float*)d_in[2];   // fp32 [128,128]
    const float* B = (const float*)d_in[3];   // fp32 [128]
    const float* A = (const float*)d_in[4];   // fp32 [32]
    float* ws  = (float*)d_ws;
    float* h   = ws + OFF_H;
    float* al  = ws + OFF_AL;
    float* ar  = ws + OFF_AR;
    float* num = ws + OFF_NUM;
    float* den = ws + OFF_DEN;
    float* deg = ws + OFF_DEG;
    float* out = (float*)d_out;

    init_kernel<<<(N_ZERO + 255) / 256, 256, 0, stream>>>(ws);
    project_kernel<<<(NN + NPB - 1) / NPB, 256, 0, stream>>>(X, W, B, A, h, al, ar);
    edge_acc_kernel<<<(NE * 128 + 255) / 256, 256, 0, stream>>>(ei, al, ar, h, num, den, deg);
    finalize_kernel<<<(NN * 128 + 255) / 256, 256, 0, stream>>>(num, den, deg, h, out);
}

// Round 3
// 355.512 us; speedup vs baseline: 1.8412x; 1.8412x over previous
//
#include <hip/hip_runtime.h>
#include <cmath>

#define NN 50000
#define NE 800000
#define NH 8
#define SLOPE 0.2f

// workspace layout (4-byte elements)
#define OFF_H    0           // float h:   6,400,000
#define OFF_AL   6400000     // float al:    400,000
#define OFF_AR   6800000     // float ar:    400,000
#define OFF_CNT  7200000     // int cnt/cursor: 50,000
#define OFF_ROW  7250000     // int row_start: 50,001
#define OFF_BSUM 7300008     // int blockSums: 256
#define OFF_CSR  7300264     // int csr_src: 800,000
#define NB_SCAN  196         // ceil(50000/256)

__global__ void init_kernel(int* __restrict__ cnt) {
    int tid = blockIdx.x * blockDim.x + threadIdx.x;
    if (tid < NN) cnt[tid] = 0;
}

// h = X @ W^T + b ; al[n,hd] = h[n,hd,:].a[:16] ; ar[n,hd] = h[n,hd,:].a[16:]
#define NPB 64   // nodes per block (8 groups x 8 iterations)
__global__ __launch_bounds__(256) void project_kernel(
    const float* __restrict__ X,   // [NN,128]
    const float* __restrict__ W,   // [128,128] row-major: W[o][k]
    const float* __restrict__ B,   // [128]
    const float* __restrict__ A,   // [32]
    float* __restrict__ h, float* __restrict__ al, float* __restrict__ ar)
{
    __shared__ float Ws[128 * 128];  // 64KB: Ws[k*128 + ((o + 4k) & 127)] = W[o][k]
    const int tid = threadIdx.x;

    for (int i = tid; i < 128 * 128; i += 256) {
        int o = i >> 7, k = i & 127;
        Ws[(k << 7) + ((o + (k << 2)) & 127)] = W[i];
    }
    __syncthreads();

    const int t32 = tid & 31;
    const int grp = tid >> 5;
    const int o4 = t32 << 2;
    float aL[4], aR[4], bv[4];
#pragma unroll
    for (int i = 0; i < 4; i++) {
        int f = (o4 + i) & 15;
        aL[i] = A[f];
        aR[i] = A[16 + f];
        bv[i] = B[o4 + i];
    }

    const int nodeBase = blockIdx.x * NPB;
    for (int it = 0; it < NPB / 8; ++it) {
        int gn = nodeBase + (it << 3) + grp;
        if (gn >= NN) continue;

        float xr[4];
#pragma unroll
        for (int j = 0; j < 4; j++) xr[j] = X[(gn << 7) + (j << 5) + t32];

        float acc0 = bv[0], acc1 = bv[1], acc2 = bv[2], acc3 = bv[3];
#pragma unroll
        for (int kk = 0; kk < 4; kk++) {
            float xrk = xr[kk];
#pragma unroll
            for (int k2 = 0; k2 < 32; k2++) {
                int k = (kk << 5) + k2;
                float xv = __shfl(xrk, k2, 32);
                const float4 wr = *(const float4*)&Ws[(k << 7) + ((o4 + (k << 2)) & 127)];
                acc0 = fmaf(xv, wr.x, acc0);
                acc1 = fmaf(xv, wr.y, acc1);
                acc2 = fmaf(xv, wr.z, acc2);
                acc3 = fmaf(xv, wr.w, acc3);
            }
        }
        *(float4*)&h[(gn << 7) + o4] = make_float4(acc0, acc1, acc2, acc3);

        float p = fmaf(acc0, aL[0], fmaf(acc1, aL[1], fmaf(acc2, aL[2], acc3 * aL[3])));
        float q = fmaf(acc0, aR[0], fmaf(acc1, aR[1], fmaf(acc2, aR[2], acc3 * aR[3])));
        p += __shfl_down(p, 2, 4);
        p += __shfl_down(p, 1, 4);
        q += __shfl_down(q, 2, 4);
        q += __shfl_down(q, 1, 4);
        if ((t32 & 3) == 0) {
            al[gn * 8 + (t32 >> 2)] = p;
            ar[gn * 8 + (t32 >> 2)] = q;
        }
    }
}

__global__ void hist_kernel(const int* __restrict__ ei, int* __restrict__ cnt) {
    int e = blockIdx.x * blockDim.x + threadIdx.x;
    if (e < NE) atomicAdd(&cnt[ei[NE + e]], 1);
}

// block-level exclusive scan; row gets local exclusive prefix, bsum gets block total
__global__ void scan1_kernel(const int* __restrict__ cnt, int* __restrict__ row,
                             int* __restrict__ bsum) {
    __shared__ int s[256];
    int tid = threadIdx.x;
    int g = blockIdx.x * 256 + tid;
    int v = (g < NN) ? cnt[g] : 0;
    s[tid] = v;
    __syncthreads();
    for (int off = 1; off < 256; off <<= 1) {
        int t = (tid >= off) ? s[tid - off] : 0;
        __syncthreads();
        s[tid] += t;
        __syncthreads();
    }
    if (g < NN) row[g] = s[tid] - v;           // local exclusive
    if (tid == 255) bsum[blockIdx.x] = s[255]; // block total
}

// exclusive scan of the block sums (NB_SCAN <= 256, single block)
__global__ void scan2_kernel(int* __restrict__ bsum) {
    __shared__ int s[256];
    int tid = threadIdx.x;
    int v = (tid < NB_SCAN) ? bsum[tid] : 0;
    s[tid] = v;
    __syncthreads();
    for (int off = 1; off < 256; off <<= 1) {
        int t = (tid >= off) ? s[tid - off] : 0;
        __syncthreads();
        s[tid] += t;
        __syncthreads();
    }
    if (tid < NB_SCAN) bsum[tid] = s[tid] - v; // exclusive
}

// row += bsum offset; copy into cursor; set row[NN] = NE
__global__ void scan3_kernel(int* __restrict__ row, const int* __restrict__ bsum,
                             int* __restrict__ cursor) {
    int tid = threadIdx.x;
    int g = blockIdx.x * 256 + tid;
    if (g < NN) {
        int r = row[g] + bsum[blockIdx.x];
        row[g] = r;
        cursor[g] = r;
    }
    if (g == 0) row[NN] = NE;
}

__global__ void scatter_kernel(const int* __restrict__ ei, int* __restrict__ cursor,
                               int* __restrict__ csr) {
    int e = blockIdx.x * blockDim.x + threadIdx.x;
    if (e >= NE) return;
    int tgt = ei[NE + e];
    int p = atomicAdd(&cursor[tgt], 1);
    csr[p] = ei[e];   // src node id
}

// one 128-thread block per target node: register-resident softmax-weighted gather
__global__ __launch_bounds__(128) void gather_kernel(
    const int* __restrict__ row, const int* __restrict__ csr,
    const float* __restrict__ al, const float* __restrict__ ar,
    const float* __restrict__ h, float* __restrict__ out)
{
    const int n = blockIdx.x;
    const int c = threadIdx.x;      // channel 0..127
    const int hh = c >> 4;          // head
    const int r0 = row[n], r1 = row[n + 1];
    const float aLt = al[n * 8 + hh];

    float acc = 0.0f, den = 0.0f;
    for (int j = r0; j < r1; ++j) {
        int src = csr[j];           // wave-uniform -> scalar load
        float v = aLt + ar[src * 8 + hh];
        v = v > 0.0f ? v : SLOPE * v;
        float ex = __expf(fminf(v, 60.0f));
        den += ex;
        acc = fmaf(ex, h[(src << 7) + c], acc);
    }
    float o = (den > 0.0f) ? acc / den : 0.0f;
    o = fmaf((float)(r1 - r0), h[(n << 7) + c], o);
    out[(n << 7) + c] = o > 0.0f ? o : expm1f(o);
}

extern "C" void kernel_launch(void* const* d_in, const int* in_sizes, int n_in,
                              void* d_out, int out_size, void* d_ws, size_t ws_size,
                              hipStream_t stream) {
    const float* X = (const float*)d_in[0];   // fp32 [NN,128]
    const int* ei  = (const int*)d_in[1];     // int32 [2,NE]
    const float* W = (const float*)d_in[2];   // fp32 [128,128]
    const float* B = (const float*)d_in[3];   // fp32 [128]
    const float* A = (const float*)d_in[4];   // fp32 [32]
    float* ws  = (float*)d_ws;
    float* h   = ws + OFF_H;
    float* al  = ws + OFF_AL;
    float* ar  = ws + OFF_AR;
    int* cnt   = (int*)ws + OFF_CNT;   // doubles as cursor
    int* rowp  = (int*)ws + OFF_ROW;
    int* bsum  = (int*)ws + OFF_BSUM;
    int* csr   = (int*)ws + OFF_CSR;
    float* out = (float*)d_out;

    init_kernel<<<NB_SCAN, 256, 0, stream>>>(cnt);
    project_kernel<<<(NN + NPB - 1) / NPB, 256, 0, stream>>>(X, W, B, A, h, al, ar);
    hist_kernel<<<(NE + 255) / 256, 256, 0, stream>>>(ei, cnt);
    scan1_kernel<<<NB_SCAN, 256, 0, stream>>>(cnt, rowp, bsum);
    scan2_kernel<<<1, 256, 0, stream>>>(bsum);
    scan3_kernel<<<NB_SCAN, 256, 0, stream>>>(rowp, bsum, cnt);
    scatter_kernel<<<(NE + 255) / 256, 256, 0, stream>>>(ei, cnt, csr);
    gather_kernel<<<NN, 128, 0, stream>>>(rowp, csr, al, ar, h, out);
}

// Round 4
// 309.202 us; speedup vs baseline: 2.1170x; 1.1498x over previous
//
#include <hip/hip_runtime.h>
#include <hip/hip_fp16.h>
#include <cmath>

#define NN 50000
#define NE 800000
#define NH 8
#define SLOPE 0.2f

// workspace layout (4-byte units)
#define OFF_H    0           // __half h: 6,400,000 halves = 3,200,000 dwords
#define OFF_AL   3200000     // float al: 400,000
#define OFF_AR   3600000     // float ar: 400,000
#define OFF_CNT  4000000     // int cnt/cursor: 50,000
#define OFF_ROW  4050000     // int row: 50,001
#define OFF_BSUM 4100064     // int blockSums: 256
#define OFF_CSR  4100320     // int csr_src: 800,000
#define NB_SCAN  196         // ceil(50000/256)

__device__ __forceinline__ float readlane_f(float v, int l) {
    return __uint_as_float(__builtin_amdgcn_readlane(__float_as_uint(v), l));
}

__global__ void init_kernel(int* __restrict__ cnt) {
    int tid = blockIdx.x * blockDim.x + threadIdx.x;
    if (tid < NN) cnt[tid] = 0;
}

// h = X @ W^T + b (stored fp16); al/ar = per-node attention dot products.
// One wave processes 8 nodes at once: X rows in VGPRs (readlane broadcast),
// W fragment from LDS reused across all 8 nodes (8x less LDS traffic).
__global__ __launch_bounds__(256) void project_kernel(
    const float* __restrict__ X,   // [NN,128]
    const float* __restrict__ W,   // [128,128] row-major W[o][k]
    const float* __restrict__ B,   // [128]
    const float* __restrict__ A,   // [32]
    __half* __restrict__ h, float* __restrict__ al, float* __restrict__ ar)
{
    __shared__ float Ws[128 * 128]; // 64KB: Ws[k*128 + ((o+2k)&127)] = W[o][k]
    const int tid = threadIdx.x;

    for (int i = tid; i < 128 * 128; i += 256) {
        int o = i >> 7, k = i & 127;
        Ws[(k << 7) + ((o + 2 * k) & 127)] = W[i];
    }
    __syncthreads();

    const int wave = tid >> 6;
    const int lane = tid & 63;
    const int o2 = lane << 1;          // 2 output features per lane

    const float b0 = B[o2], b1 = B[o2 + 1];
    const float aL0 = A[o2 & 15], aL1 = A[(o2 + 1) & 15];
    const float aR0 = A[16 + (o2 & 15)], aR1 = A[16 + ((o2 + 1) & 15)];

    const int blockBase = blockIdx.x * 64;
    for (int it = 0; it < 2; ++it) {
        const int n0 = blockBase + it * 32 + wave * 8;  // 8 nodes for this wave

        float xr[8][2];
#pragma unroll
        for (int nd = 0; nd < 8; nd++) {
            int gn = n0 + nd;
#pragma unroll
            for (int j = 0; j < 2; j++)
                xr[nd][j] = (gn < NN) ? X[(gn << 7) + (j << 6) + lane] : 0.0f;
        }

        float acc[8][2];
#pragma unroll
        for (int nd = 0; nd < 8; nd++) { acc[nd][0] = b0; acc[nd][1] = b1; }

#pragma unroll
        for (int j = 0; j < 2; j++) {            // k half: j*64 .. j*64+63
            for (int kk = 0; kk < 64; kk += 4) { // runtime loop, 16 iters
                float wv[4][2];
#pragma unroll
                for (int dk = 0; dk < 4; dk++) {
                    int k = (j << 6) + kk + dk;
                    const float2 wp = *(const float2*)&Ws[(k << 7) + ((o2 + 2 * k) & 127)];
                    wv[dk][0] = wp.x; wv[dk][1] = wp.y;
                }
#pragma unroll
                for (int nd = 0; nd < 8; nd++) {
#pragma unroll
                    for (int dk = 0; dk < 4; dk++) {
                        float xv = readlane_f(xr[nd][j], kk + dk);
                        acc[nd][0] = fmaf(xv, wv[dk][0], acc[nd][0]);
                        acc[nd][1] = fmaf(xv, wv[dk][1], acc[nd][1]);
                    }
                }
            }
        }

#pragma unroll
        for (int nd = 0; nd < 8; nd++) {
            int gn = n0 + nd;
            if (gn >= NN) continue;   // uniform across wave
            float a0 = acc[nd][0], a1 = acc[nd][1];
            *(__half2*)&h[(gn << 7) + o2] = __float22half2_rn(make_float2(a0, a1));
            float p = fmaf(a0, aL0, a1 * aL1);
            float q = fmaf(a0, aR0, a1 * aR1);
            p += __shfl_xor(p, 1); p += __shfl_xor(p, 2); p += __shfl_xor(p, 4);
            q += __shfl_xor(q, 1); q += __shfl_xor(q, 2); q += __shfl_xor(q, 4);
            if ((lane & 7) == 0) {
                al[gn * 8 + (lane >> 3)] = p;
                ar[gn * 8 + (lane >> 3)] = q;
            }
        }
    }
}

__global__ void hist_kernel(const int* __restrict__ ei, int* __restrict__ cnt) {
    int e = blockIdx.x * blockDim.x + threadIdx.x;
    if (e < NE) atomicAdd(&cnt[ei[NE + e]], 1);
}

__global__ void scan1_kernel(const int* __restrict__ cnt, int* __restrict__ row,
                             int* __restrict__ bsum) {
    __shared__ int s[256];
    int tid = threadIdx.x;
    int g = blockIdx.x * 256 + tid;
    int v = (g < NN) ? cnt[g] : 0;
    s[tid] = v;
    __syncthreads();
    for (int off = 1; off < 256; off <<= 1) {
        int t = (tid >= off) ? s[tid - off] : 0;
        __syncthreads();
        s[tid] += t;
        __syncthreads();
    }
    if (g < NN) row[g] = s[tid] - v;
    if (tid == 255) bsum[blockIdx.x] = s[255];
}

__global__ void scan2_kernel(int* __restrict__ bsum) {
    __shared__ int s[256];
    int tid = threadIdx.x;
    int v = (tid < NB_SCAN) ? bsum[tid] : 0;
    s[tid] = v;
    __syncthreads();
    for (int off = 1; off < 256; off <<= 1) {
        int t = (tid >= off) ? s[tid - off] : 0;
        __syncthreads();
        s[tid] += t;
        __syncthreads();
    }
    if (tid < NB_SCAN) bsum[tid] = s[tid] - v;
}

__global__ void scan3_kernel(int* __restrict__ row, const int* __restrict__ bsum,
                             int* __restrict__ cursor) {
    int tid = threadIdx.x;
    int g = blockIdx.x * 256 + tid;
    if (g < NN) {
        int r = row[g] + bsum[blockIdx.x];
        row[g] = r;
        cursor[g] = r;
    }
    if (g == 0) row[NN] = NE;
}

__global__ void scatter_kernel(const int* __restrict__ ei, int* __restrict__ cursor,
                               int* __restrict__ csr) {
    int e = blockIdx.x * blockDim.x + threadIdx.x;
    if (e >= NE) return;
    int tgt = ei[NE + e];
    int p = atomicAdd(&cursor[tgt], 1);
    csr[p] = ei[e];
}

// one wave per target node; lane covers 2 channels (half2); 2-edge unroll
__global__ __launch_bounds__(256) void gather_kernel(
    const int* __restrict__ row, const int* __restrict__ csr,
    const float* __restrict__ al, const float* __restrict__ ar,
    const __half* __restrict__ h, float* __restrict__ out)
{
    const int n = blockIdx.x * 4 + (threadIdx.x >> 6);
    if (n >= NN) return;
    const int lane = threadIdx.x & 63;
    const int c2 = lane << 1;
    const int hh = lane >> 3;
    const int r0 = row[n], r1 = row[n + 1];
    const float aLt = al[n * 8 + hh];

    float acc0 = 0.0f, acc1 = 0.0f, den = 0.0f;
    int j = r0;
    for (; j + 1 < r1; j += 2) {
        int s0 = csr[j], s1 = csr[j + 1];
        float v0 = aLt + ar[s0 * 8 + hh];
        float v1 = aLt + ar[s1 * 8 + hh];
        v0 = v0 > 0.0f ? v0 : SLOPE * v0;
        v1 = v1 > 0.0f ? v1 : SLOPE * v1;
        float e0 = __expf(fminf(v0, 60.0f));
        float e1 = __expf(fminf(v1, 60.0f));
        float2 h0 = __half22float2(*(const __half2*)&h[(s0 << 7) + c2]);
        float2 h1 = __half22float2(*(const __half2*)&h[(s1 << 7) + c2]);
        den += e0 + e1;
        acc0 = fmaf(e0, h0.x, fmaf(e1, h1.x, acc0));
        acc1 = fmaf(e0, h0.y, fmaf(e1, h1.y, acc1));
    }
    if (j < r1) {
        int s0 = csr[j];
        float v0 = aLt + ar[s0 * 8 + hh];
        v0 = v0 > 0.0f ? v0 : SLOPE * v0;
        float e0 = __expf(fminf(v0, 60.0f));
        float2 h0 = __half22float2(*(const __half2*)&h[(s0 << 7) + c2]);
        den += e0;
        acc0 = fmaf(e0, h0.x, acc0);
        acc1 = fmaf(e0, h0.y, acc1);
    }

    float2 hs = __half22float2(*(const __half2*)&h[(n << 7) + c2]);
    float degf = (float)(r1 - r0);
    float inv = (den > 0.0f) ? 1.0f / den : 0.0f;
    float o0 = fmaf(degf, hs.x, acc0 * inv);
    float o1 = fmaf(degf, hs.y, acc1 * inv);
    o0 = o0 > 0.0f ? o0 : expm1f(o0);
    o1 = o1 > 0.0f ? o1 : expm1f(o1);
    *(float2*)&out[(n << 7) + c2] = make_float2(o0, o1);
}

extern "C" void kernel_launch(void* const* d_in, const int* in_sizes, int n_in,
                              void* d_out, int out_size, void* d_ws, size_t ws_size,
                              hipStream_t stream) {
    const float* X = (const float*)d_in[0];
    const int* ei  = (const int*)d_in[1];
    const float* W = (const float*)d_in[2];
    const float* B = (const float*)d_in[3];
    const float* A = (const float*)d_in[4];
    float* ws  = (float*)d_ws;
    __half* h  = (__half*)(ws + OFF_H);
    float* al  = ws + OFF_AL;
    float* ar  = ws + OFF_AR;
    int* cnt   = (int*)ws + OFF_CNT;
    int* rowp  = (int*)ws + OFF_ROW;
    int* bsum  = (int*)ws + OFF_BSUM;
    int* csr   = (int*)ws + OFF_CSR;
    float* out = (float*)d_out;

    init_kernel<<<NB_SCAN, 256, 0, stream>>>(cnt);
    project_kernel<<<(NN + 63) / 64, 256, 0, stream>>>(X, W, B, A, h, al, ar);
    hist_kernel<<<(NE + 255) / 256, 256, 0, stream>>>(ei, cnt);
    scan1_kernel<<<NB_SCAN, 256, 0, stream>>>(cnt, rowp, bsum);
    scan2_kernel<<<1, 256, 0, stream>>>(bsum);
    scan3_kernel<<<NB_SCAN, 256, 0, stream>>>(rowp, bsum, cnt);
    scatter_kernel<<<(NE + 255) / 256, 256, 0, stream>>>(ei, cnt, csr);
    gather_kernel<<<(NN + 3) / 4, 256, 0, stream>>>(rowp, csr, al, ar, h, out);
}

// Round 6
// 249.161 us; speedup vs baseline: 2.6271x; 1.2410x over previous
//
#include <hip/hip_runtime.h>
#include <hip/hip_fp16.h>
#include <cmath>

#define NN 50000
#define NE 800000
#define NH 8
#define SLOPE 0.2f

// workspace layout (4-byte units)
#define OFF_H    0           // __half h: 6,400,000 halves = 3,200,000 dwords
#define OFF_AL   3200000     // float al: 400,000
#define OFF_AR   3600000     // float ar: 400,000
#define OFF_CNT  4000000     // int cnt/cursor: 50,000
#define OFF_ROW  4050000     // int row: 50,001
#define OFF_BSUM 4100064     // int blockSums: 256
#define OFF_CSR  4100320     // int csr_src: 800,000
#define NB_SCAN  196         // ceil(50000/256)

using half8   = __attribute__((ext_vector_type(8))) _Float16;
using floatx4 = __attribute__((ext_vector_type(4))) float;

__global__ void init_kernel(int* __restrict__ cnt) {
    int tid = blockIdx.x * blockDim.x + threadIdx.x;
    if (tid < NN) cnt[tid] = 0;
}

// MFMA projection: h = fp16(X @ W^T + b); al/ar = per-node attention dots.
// One wave = 16 nodes x 128 outputs via mfma_f32_16x16x32_f16 (8 N-tiles, K=128).
// W staged fp16 in LDS (stride 136 halfs: 16B-aligned rows).
#define WST 136
__global__ __launch_bounds__(256) void project_kernel(
    const float* __restrict__ X,    // [NN,128]
    const float* __restrict__ W,    // [128,128] row-major W[o][k] == B-operand [N][K]
    const float* __restrict__ Bv,   // [128]
    const float* __restrict__ Av,   // [32]
    __half* __restrict__ h, float* __restrict__ al, float* __restrict__ ar)
{
    __shared__ _Float16 Wh[128 * WST];   // 34.8 KB
    __shared__ _Float16 Cs[64 * WST];    // 17.4 KB: block's 64-node output tile
    __shared__ float As[32];
    const int tid = threadIdx.x;

    for (int i = tid; i < 128 * 128; i += 256) {
        int o = i >> 7, k = i & 127;
        Wh[o * WST + k] = (_Float16)W[i];
    }
    if (tid < 32) As[tid] = Av[tid];
    __syncthreads();

    const int wave = tid >> 6;
    const int lane = tid & 63;
    const int q = lane >> 4;       // quad 0..3
    const int n = lane & 15;       // col within 16-tile
    const int node0 = blockIdx.x * 64 + wave * 16;

    // A fragments: afrag[kc][j] = X[node0+n][kc*32 + q*8 + j], fp32->fp16
    const int gn = node0 + n;
    const bool valid = gn < NN;
    const float* xrow = X + ((long)gn << 7);
    half8 afrag[4];
#pragma unroll
    for (int kc = 0; kc < 4; ++kc) {
        float4 x0 = make_float4(0.f, 0.f, 0.f, 0.f), x1 = x0;
        if (valid) {
            x0 = *(const float4*)(xrow + kc * 32 + q * 8);
            x1 = *(const float4*)(xrow + kc * 32 + q * 8 + 4);
        }
        half8 a;
        a[0] = (_Float16)x0.x; a[1] = (_Float16)x0.y;
        a[2] = (_Float16)x0.z; a[3] = (_Float16)x0.w;
        a[4] = (_Float16)x1.x; a[5] = (_Float16)x1.y;
        a[6] = (_Float16)x1.z; a[7] = (_Float16)x1.w;
        afrag[kc] = a;
    }

    floatx4 acc[8];
#pragma unroll
    for (int nt = 0; nt < 8; ++nt) {
        float b = Bv[nt * 16 + n];
        acc[nt][0] = b; acc[nt][1] = b; acc[nt][2] = b; acc[nt][3] = b;
    }

#pragma unroll
    for (int nt = 0; nt < 8; ++nt) {
        const _Float16* wrow = &Wh[(nt * 16 + n) * WST];
#pragma unroll
        for (int kc = 0; kc < 4; ++kc) {
            half8 bfrag = *(const half8*)(wrow + kc * 32 + q * 8);
            acc[nt] = __builtin_amdgcn_mfma_f32_16x16x32_f16(afrag[kc], bfrag, acc[nt], 0, 0, 0);
        }
    }

    // C/D layout: lane holds C[m=q*4+r][n] -> stage to Cs[node][feature]
    _Float16* cw = &Cs[(wave * 16) * WST];
#pragma unroll
    for (int nt = 0; nt < 8; ++nt) {
#pragma unroll
        for (int r = 0; r < 4; ++r) {
            cw[(q * 4 + r) * WST + nt * 16 + n] = (_Float16)acc[nt][r];
        }
    }
    __syncthreads();

    // coalesced h write: thread -> (row = tid>>2, 32-half chunk = tid&3) = 64B each
    {
        int row = tid >> 2, ch = tid & 3;
        int gnode = blockIdx.x * 64 + row;
        if (gnode < NN) {
            const uint4* src = (const uint4*)&Cs[row * WST + ch * 32];
            uint4* dst = (uint4*)&h[((long)gnode << 7) + ch * 32];
            dst[0] = src[0];
            dst[1] = src[1];
            dst[2] = src[2];
            dst[3] = src[3];
        }
    }
    // al/ar: 64 nodes x 8 heads = 512 pairs, 2 per thread
    for (int p = tid; p < 512; p += 256) {
        int nd = p >> 3, hh = p & 7;
        int gnode = blockIdx.x * 64 + nd;
        if (gnode >= NN) continue;
        const _Float16* c = &Cs[nd * WST + hh * 16];
        float pL = 0.f, pR = 0.f;
#pragma unroll
        for (int f = 0; f < 16; ++f) {
            float hv = (float)c[f];
            pL = fmaf(hv, As[f], pL);
            pR = fmaf(hv, As[16 + f], pR);
        }
        al[gnode * 8 + hh] = pL;
        ar[gnode * 8 + hh] = pR;
    }
}

__global__ void hist_kernel(const int* __restrict__ ei, int* __restrict__ cnt) {
    int e = blockIdx.x * blockDim.x + threadIdx.x;
    if (e < NE) atomicAdd(&cnt[ei[NE + e]], 1);
}

__global__ void scan1_kernel(const int* __restrict__ cnt, int* __restrict__ row,
                             int* __restrict__ bsum) {
    __shared__ int s[256];
    int tid = threadIdx.x;
    int g = blockIdx.x * 256 + tid;
    int v = (g < NN) ? cnt[g] : 0;
    s[tid] = v;
    __syncthreads();
    for (int off = 1; off < 256; off <<= 1) {
        int t = (tid >= off) ? s[tid - off] : 0;
        __syncthreads();
        s[tid] += t;
        __syncthreads();
    }
    if (g < NN) row[g] = s[tid] - v;
    if (tid == 255) bsum[blockIdx.x] = s[255];
}

__global__ void scan2_kernel(int* __restrict__ bsum) {
    __shared__ int s[256];
    int tid = threadIdx.x;
    int v = (tid < NB_SCAN) ? bsum[tid] : 0;
    s[tid] = v;
    __syncthreads();
    for (int off = 1; off < 256; off <<= 1) {
        int t = (tid >= off) ? s[tid - off] : 0;
        __syncthreads();
        s[tid] += t;
        __syncthreads();
    }
    if (tid < NB_SCAN) bsum[tid] = s[tid] - v;
}

__global__ void scan3_kernel(int* __restrict__ row, const int* __restrict__ bsum,
                             int* __restrict__ cursor) {
    int tid = threadIdx.x;
    int g = blockIdx.x * 256 + tid;
    if (g < NN) {
        int r = row[g] + bsum[blockIdx.x];
        row[g] = r;
        cursor[g] = r;
    }
    if (g == 0) row[NN] = NE;
}

__global__ void scatter_kernel(const int* __restrict__ ei, int* __restrict__ cursor,
                               int* __restrict__ csr) {
    int e = blockIdx.x * blockDim.x + threadIdx.x;
    if (e >= NE) return;
    int tgt = ei[NE + e];
    int p = atomicAdd(&cursor[tgt], 1);
    csr[p] = ei[e];
}

// one wave per target node; lane covers 2 channels (half2); 2-edge unroll
__global__ __launch_bounds__(256) void gather_kernel(
    const int* __restrict__ row, const int* __restrict__ csr,
    const float* __restrict__ al, const float* __restrict__ ar,
    const __half* __restrict__ h, float* __restrict__ out)
{
    const int n = blockIdx.x * 4 + (threadIdx.x >> 6);
    if (n >= NN) return;
    const int lane = threadIdx.x & 63;
    const int c2 = lane << 1;
    const int hh = lane >> 3;
    const int r0 = row[n], r1 = row[n + 1];
    const float aLt = al[n * 8 + hh];

    float acc0 = 0.0f, acc1 = 0.0f, den = 0.0f;
    int j = r0;
    for (; j + 1 < r1; j += 2) {
        int s0 = csr[j], s1 = csr[j + 1];
        float v0 = aLt + ar[s0 * 8 + hh];
        float v1 = aLt + ar[s1 * 8 + hh];
        v0 = v0 > 0.0f ? v0 : SLOPE * v0;
        v1 = v1 > 0.0f ? v1 : SLOPE * v1;
        float e0 = __expf(fminf(v0, 60.0f));
        float e1 = __expf(fminf(v1, 60.0f));
        float2 h0 = __half22float2(*(const __half2*)&h[(s0 << 7) + c2]);
        float2 h1 = __half22float2(*(const __half2*)&h[(s1 << 7) + c2]);
        den += e0 + e1;
        acc0 = fmaf(e0, h0.x, fmaf(e1, h1.x, acc0));
        acc1 = fmaf(e0, h0.y, fmaf(e1, h1.y, acc1));
    }
    if (j < r1) {
        int s0 = csr[j];
        float v0 = aLt + ar[s0 * 8 + hh];
        v0 = v0 > 0.0f ? v0 : SLOPE * v0;
        float e0 = __expf(fminf(v0, 60.0f));
        float2 h0 = __half22float2(*(const __half2*)&h[(s0 << 7) + c2]);
        den += e0;
        acc0 = fmaf(e0, h0.x, acc0);
        acc1 = fmaf(e0, h0.y, acc1);
    }

    float2 hs = __half22float2(*(const __half2*)&h[(n << 7) + c2]);
    float degf = (float)(r1 - r0);
    float inv = (den > 0.0f) ? 1.0f / den : 0.0f;
    float o0 = fmaf(degf, hs.x, acc0 * inv);
    float o1 = fmaf(degf, hs.y, acc1 * inv);
    o0 = o0 > 0.0f ? o0 : expm1f(o0);
    o1 = o1 > 0.0f ? o1 : expm1f(o1);
    *(float2*)&out[(n << 7) + c2] = make_float2(o0, o1);
}

extern "C" void kernel_launch(void* const* d_in, const int* in_sizes, int n_in,
                              void* d_out, int out_size, void* d_ws, size_t ws_size,
                              hipStream_t stream) {
    const float* X = (const float*)d_in[0];
    const int* ei  = (const int*)d_in[1];
    const float* W = (const float*)d_in[2];
    const float* B = (const float*)d_in[3];
    const float* A = (const float*)d_in[4];
    float* ws  = (float*)d_ws;
    __half* h  = (__half*)(ws + OFF_H);
    float* al  = ws + OFF_AL;
    float* ar  = ws + OFF_AR;
    int* cnt   = (int*)ws + OFF_CNT;
    int* rowp  = (int*)ws + OFF_ROW;
    int* bsum  = (int*)ws + OFF_BSUM;
    int* csr   = (int*)ws + OFF_CSR;
    float* out = (float*)d_out;

    init_kernel<<<NB_SCAN, 256, 0, stream>>>(cnt);
    project_kernel<<<(NN + 63) / 64, 256, 0, stream>>>(X, W, B, A, h, al, ar);
    hist_kernel<<<(NE + 255) / 256, 256, 0, stream>>>(ei, cnt);
    scan1_kernel<<<NB_SCAN, 256, 0, stream>>>(cnt, rowp, bsum);
    scan2_kernel<<<1, 256, 0, stream>>>(bsum);
    scan3_kernel<<<NB_SCAN, 256, 0, stream>>>(rowp, bsum, cnt);
    scatter_kernel<<<(NE + 255) / 256, 256, 0, stream>>>(ei, cnt, csr);
    gather_kernel<<<(NN + 3) / 4, 256, 0, stream>>>(rowp, csr, al, ar, h, out);
}

// Round 7
// 231.269 us; speedup vs baseline: 2.8303x; 1.0774x over previous
//
#include <hip/hip_runtime.h>
#include <hip/hip_fp16.h>
#include <cmath>

#define NN 50000
#define NE 800000
#define NH 8
#define SLOPE 0.2f

// workspace layout (4-byte units)
#define OFF_H    0           // __half h: 6,400,000 halves = 3,200,000 dwords
#define OFF_H8   3200000     // fp8 h8: 6,400,000 bytes = 1,600,000 dwords
#define OFF_AL   4800000     // float al: 400,000
#define OFF_AR   5200000     // float ar: 400,000
#define OFF_CNT  5600000     // int cnt: 50,000
#define OFF_CUR  5650000     // int cursor: 50,000 (contiguous with cnt for one memset)
#define OFF_ROW  5700000     // int row (block-local exclusive prefix): 50,000
#define OFF_BSUM 5750000     // int blockSums: 256
#define OFF_CSR  5750256     // int csr_src: 800,000
#define NB_SCAN  196         // ceil(50000/256)

using half8   = __attribute__((ext_vector_type(8))) _Float16;
using floatx4 = __attribute__((ext_vector_type(4))) float;
using floatx2 = __attribute__((ext_vector_type(2))) float;

// MFMA projection: h = fp16(X @ W^T + b), h8 = fp8(same); al/ar = attention dots.
#define WST 136
__global__ __launch_bounds__(256) void project_kernel(
    const float* __restrict__ X,    // [NN,128]
    const float* __restrict__ W,    // [128,128] row-major W[o][k] == B-operand [N][K]
    const float* __restrict__ Bv,   // [128]
    const float* __restrict__ Av,   // [32]
    __half* __restrict__ h, unsigned char* __restrict__ h8,
    float* __restrict__ al, float* __restrict__ ar)
{
    __shared__ _Float16 Wh[128 * WST];   // 34.8 KB
    __shared__ _Float16 Cs[64 * WST];    // 17.4 KB
    __shared__ float As[32];
    const int tid = threadIdx.x;

    for (int i = tid; i < 128 * 128; i += 256) {
        int o = i >> 7, k = i & 127;
        Wh[o * WST + k] = (_Float16)W[i];
    }
    if (tid < 32) As[tid] = Av[tid];
    __syncthreads();

    const int wave = tid >> 6;
    const int lane = tid & 63;
    const int q = lane >> 4;
    const int n = lane & 15;
    const int node0 = blockIdx.x * 64 + wave * 16;

    const int gn = node0 + n;
    const bool valid = gn < NN;
    const float* xrow = X + ((long)gn << 7);
    half8 afrag[4];
#pragma unroll
    for (int kc = 0; kc < 4; ++kc) {
        float4 x0 = make_float4(0.f, 0.f, 0.f, 0.f), x1 = x0;
        if (valid) {
            x0 = *(const float4*)(xrow + kc * 32 + q * 8);
            x1 = *(const float4*)(xrow + kc * 32 + q * 8 + 4);
        }
        half8 a;
        a[0] = (_Float16)x0.x; a[1] = (_Float16)x0.y;
        a[2] = (_Float16)x0.z; a[3] = (_Float16)x0.w;
        a[4] = (_Float16)x1.x; a[5] = (_Float16)x1.y;
        a[6] = (_Float16)x1.z; a[7] = (_Float16)x1.w;
        afrag[kc] = a;
    }

    floatx4 acc[8];
#pragma unroll
    for (int nt = 0; nt < 8; ++nt) {
        float b = Bv[nt * 16 + n];
        acc[nt][0] = b; acc[nt][1] = b; acc[nt][2] = b; acc[nt][3] = b;
    }

#pragma unroll
    for (int nt = 0; nt < 8; ++nt) {
        const _Float16* wrow = &Wh[(nt * 16 + n) * WST];
#pragma unroll
        for (int kc = 0; kc < 4; ++kc) {
            half8 bfrag = *(const half8*)(wrow + kc * 32 + q * 8);
            acc[nt] = __builtin_amdgcn_mfma_f32_16x16x32_f16(afrag[kc], bfrag, acc[nt], 0, 0, 0);
        }
    }

    // C/D layout: lane holds C[m=q*4+r][n] -> Cs[node][feature]
    _Float16* cw = &Cs[(wave * 16) * WST];
#pragma unroll
    for (int nt = 0; nt < 8; ++nt) {
#pragma unroll
        for (int r = 0; r < 4; ++r) {
            cw[(q * 4 + r) * WST + nt * 16 + n] = (_Float16)acc[nt][r];
        }
    }
    __syncthreads();

    // h (fp16) + h8 (fp8) writes: thread -> (row = tid>>2, 32-feature chunk = tid&3)
    {
        int row = tid >> 2, ch = tid & 3;
        int gnode = blockIdx.x * 64 + row;
        if (gnode < NN) {
            const uint4* src = (const uint4*)&Cs[row * WST + ch * 32];
            uint4 v[4] = { src[0], src[1], src[2], src[3] };  // 32 halfs
            uint4* dst = (uint4*)&h[((long)gnode << 7) + ch * 32];
            dst[0] = v[0]; dst[1] = v[1]; dst[2] = v[2]; dst[3] = v[3];

            const unsigned int* dw = (const unsigned int*)v;  // 16 dwords = 32 halfs
            unsigned int res[8];
#pragma unroll
            for (int w = 0; w < 8; ++w) {
                unsigned int lo = dw[2 * w], hi = dw[2 * w + 1];
                float2 f0 = __half22float2(*(const __half2*)&lo);
                float2 f1 = __half22float2(*(const __half2*)&hi);
                unsigned int r = 0;
                r = __builtin_amdgcn_cvt_pk_fp8_f32(f0.x, f0.y, r, false);
                r = __builtin_amdgcn_cvt_pk_fp8_f32(f1.x, f1.y, r, true);
                res[w] = r;
            }
            uint4* d8 = (uint4*)&h8[((long)gnode << 7) + ch * 32];
            d8[0] = make_uint4(res[0], res[1], res[2], res[3]);
            d8[1] = make_uint4(res[4], res[5], res[6], res[7]);
        }
    }
    // al/ar: 64 nodes x 8 heads, 2 per thread
    for (int p = tid; p < 512; p += 256) {
        int nd = p >> 3, hh = p & 7;
        int gnode = blockIdx.x * 64 + nd;
        if (gnode >= NN) continue;
        const _Float16* c = &Cs[nd * WST + hh * 16];
        float pL = 0.f, pR = 0.f;
#pragma unroll
        for (int f = 0; f < 16; ++f) {
            float hv = (float)c[f];
            pL = fmaf(hv, As[f], pL);
            pR = fmaf(hv, As[16 + f], pR);
        }
        al[gnode * 8 + hh] = pL;
        ar[gnode * 8 + hh] = pR;
    }
}

__global__ void hist_kernel(const int* __restrict__ ei, int* __restrict__ cnt) {
    int e = blockIdx.x * blockDim.x + threadIdx.x;
    if (e < NE) atomicAdd(&cnt[ei[NE + e]], 1);
}

// block-local exclusive scan; bsum gets block totals
__global__ void scan1_kernel(const int* __restrict__ cnt, int* __restrict__ row,
                             int* __restrict__ bsum) {
    __shared__ int s[256];
    int tid = threadIdx.x;
    int g = blockIdx.x * 256 + tid;
    int v = (g < NN) ? cnt[g] : 0;
    s[tid] = v;
    __syncthreads();
    for (int off = 1; off < 256; off <<= 1) {
        int t = (tid >= off) ? s[tid - off] : 0;
        __syncthreads();
        s[tid] += t;
        __syncthreads();
    }
    if (g < NN) row[g] = s[tid] - v;
    if (tid == 255) bsum[blockIdx.x] = s[255];
}

// exclusive scan of block sums (NB_SCAN <= 256, single block)
__global__ void scan2_kernel(int* __restrict__ bsum) {
    __shared__ int s[256];
    int tid = threadIdx.x;
    int v = (tid < NB_SCAN) ? bsum[tid] : 0;
    s[tid] = v;
    __syncthreads();
    for (int off = 1; off < 256; off <<= 1) {
        int t = (tid >= off) ? s[tid - off] : 0;
        __syncthreads();
        s[tid] += t;
        __syncthreads();
    }
    if (tid < NB_SCAN) bsum[tid] = s[tid] - v;
}

__global__ void scatter_kernel(const int* __restrict__ ei,
                               const int* __restrict__ row, const int* __restrict__ bsum,
                               int* __restrict__ cur, int* __restrict__ csr) {
    int e = blockIdx.x * blockDim.x + threadIdx.x;
    if (e >= NE) return;
    int tgt = ei[NE + e];
    int p = row[tgt] + bsum[tgt >> 8] + atomicAdd(&cur[tgt], 1);
    csr[p] = ei[e];
}

// one wave per target node; lane covers 2 channels; fp8 neighbor reads, 4-edge unroll
__global__ __launch_bounds__(256) void gather_kernel(
    const int* __restrict__ row, const int* __restrict__ bsum,
    const int* __restrict__ cnt, const int* __restrict__ csr,
    const float* __restrict__ al, const float* __restrict__ ar,
    const __half* __restrict__ h, const unsigned char* __restrict__ h8,
    float* __restrict__ out)
{
    const int n = blockIdx.x * 4 + (threadIdx.x >> 6);
    if (n >= NN) return;
    const int lane = threadIdx.x & 63;
    const int c2 = lane << 1;
    const int hh = lane >> 3;
    const int r0 = row[n] + bsum[n >> 8];
    const int deg = cnt[n];
    const int r1 = r0 + deg;
    const float aLt = al[n * 8 + hh];

    float acc0 = 0.0f, acc1 = 0.0f, den = 0.0f;
    int j = r0;
    for (; j + 3 < r1; j += 4) {
        int s0 = csr[j], s1 = csr[j + 1], s2 = csr[j + 2], s3 = csr[j + 3];
        float v0 = aLt + ar[s0 * 8 + hh];
        float v1 = aLt + ar[s1 * 8 + hh];
        float v2 = aLt + ar[s2 * 8 + hh];
        float v3 = aLt + ar[s3 * 8 + hh];
        unsigned short u0 = *(const unsigned short*)&h8[((long)s0 << 7) + c2];
        unsigned short u1 = *(const unsigned short*)&h8[((long)s1 << 7) + c2];
        unsigned short u2 = *(const unsigned short*)&h8[((long)s2 << 7) + c2];
        unsigned short u3 = *(const unsigned short*)&h8[((long)s3 << 7) + c2];
        v0 = v0 > 0.0f ? v0 : SLOPE * v0;
        v1 = v1 > 0.0f ? v1 : SLOPE * v1;
        v2 = v2 > 0.0f ? v2 : SLOPE * v2;
        v3 = v3 > 0.0f ? v3 : SLOPE * v3;
        float e0 = __expf(fminf(v0, 60.0f));
        float e1 = __expf(fminf(v1, 60.0f));
        float e2 = __expf(fminf(v2, 60.0f));
        float e3 = __expf(fminf(v3, 60.0f));
        floatx2 g0 = __builtin_amdgcn_cvt_pk_f32_fp8(u0, false);
        floatx2 g1 = __builtin_amdgcn_cvt_pk_f32_fp8(u1, false);
        floatx2 g2 = __builtin_amdgcn_cvt_pk_f32_fp8(u2, false);
        floatx2 g3 = __builtin_amdgcn_cvt_pk_f32_fp8(u3, false);
        den += (e0 + e1) + (e2 + e3);
        acc0 = fmaf(e0, g0[0], fmaf(e1, g1[0], fmaf(e2, g2[0], fmaf(e3, g3[0], acc0))));
        acc1 = fmaf(e0, g0[1], fmaf(e1, g1[1], fmaf(e2, g2[1], fmaf(e3, g3[1], acc1))));
    }
    for (; j < r1; ++j) {
        int s0 = csr[j];
        float v0 = aLt + ar[s0 * 8 + hh];
        v0 = v0 > 0.0f ? v0 : SLOPE * v0;
        float e0 = __expf(fminf(v0, 60.0f));
        unsigned short u0 = *(const unsigned short*)&h8[((long)s0 << 7) + c2];
        floatx2 g0 = __builtin_amdgcn_cvt_pk_f32_fp8(u0, false);
        den += e0;
        acc0 = fmaf(e0, g0[0], acc0);
        acc1 = fmaf(e0, g0[1], acc1);
    }

    float2 hs = __half22float2(*(const __half2*)&h[((long)n << 7) + c2]);
    float degf = (float)deg;
    float inv = (den > 0.0f) ? 1.0f / den : 0.0f;
    float o0 = fmaf(degf, hs.x, acc0 * inv);
    float o1 = fmaf(degf, hs.y, acc1 * inv);
    o0 = o0 > 0.0f ? o0 : expm1f(o0);
    o1 = o1 > 0.0f ? o1 : expm1f(o1);
    *(float2*)&out[((long)n << 7) + c2] = make_float2(o0, o1);
}

extern "C" void kernel_launch(void* const* d_in, const int* in_sizes, int n_in,
                              void* d_out, int out_size, void* d_ws, size_t ws_size,
                              hipStream_t stream) {
    const float* X = (const float*)d_in[0];
    const int* ei  = (const int*)d_in[1];
    const float* W = (const float*)d_in[2];
    const float* B = (const float*)d_in[3];
    const float* A = (const float*)d_in[4];
    float* ws  = (float*)d_ws;
    __half* h  = (__half*)(ws + OFF_H);
    unsigned char* h8 = (unsigned char*)(ws + OFF_H8);
    float* al  = ws + OFF_AL;
    float* ar  = ws + OFF_AR;
    int* cnt   = (int*)ws + OFF_CNT;
    int* cur   = (int*)ws + OFF_CUR;
    int* rowp  = (int*)ws + OFF_ROW;
    int* bsum  = (int*)ws + OFF_BSUM;
    int* csr   = (int*)ws + OFF_CSR;
    float* out = (float*)d_out;

    hipMemsetAsync(cnt, 0, 100000 * sizeof(int), stream);  // cnt + cur
    project_kernel<<<(NN + 63) / 64, 256, 0, stream>>>(X, W, B, A, h, h8, al, ar);
    hist_kernel<<<(NE + 255) / 256, 256, 0, stream>>>(ei, cnt);
    scan1_kernel<<<NB_SCAN, 256, 0, stream>>>(cnt, rowp, bsum);
    scan2_kernel<<<1, 256, 0, stream>>>(bsum);
    scatter_kernel<<<(NE + 255) / 256, 256, 0, stream>>>(ei, rowp, bsum, cur, csr);
    gather_kernel<<<(NN + 3) / 4, 256, 0, stream>>>(rowp, bsum, cnt, csr, al, ar, h, h8, out);
}